// Round 4
// baseline (76.914 us; speedup 1.0000x reference)
//
#include <hip/hip_runtime.h>
#include <math.h>

#define HW_SZ 32768
#define C_SZ  256
#define L_SZ  5
#define CHW   (C_SZ * HW_SZ)     // 8,388,608 elements (int-safe)

typedef float vfloat4 __attribute__((ext_vector_type(4)));

// ---------------------------------------------------------------------------
// R4: persistent 2-tile pipeline. R3 geometry (1024 threads / 16 waves, 64-n
// tile, atom-complete 256-B stores), but grid = 256 blocks (1/CU) and each
// block processes 2 consecutive tiles. Tile A's nt stores are fire-and-forget
// in the vmem queue and DRAIN WHILE tile B's 20 loads issue+complete -> reads
// and writes concurrent at the HBM controller (mixed ~6.3 TB/s aggregate)
// instead of a uni-directional write phase (~4.5 TB/s measured from R3:
// 65.4 us = 16 us reads + ~5 us reduce + ~44 us writes-only).
//
// Critical detail: __syncthreads() would emit s_waitcnt vmcnt(0) before
// s_barrier, forcing tile-A stores to complete before tile-B's reduce. All
// in-loop barriers are raw s_barrier + lgkmcnt(0)-only. This is safe: the
// ONLY cross-thread dependencies in this block are LDS (part/m_sh/w_sh);
// no thread ever reads another thread's global stores, and all global loads
// are consumed (vmcnt-waited at use) before each barrier anyway.
// #pragma unroll 1 keeps the tile loop single-buffered (no 2x v[] regs).
// ---------------------------------------------------------------------------

__device__ __forceinline__ void sync_lds_only() {
    // make my LDS writes visible, then rendezvous; do NOT drain vmcnt
    asm volatile("s_waitcnt lgkmcnt(0)" ::: "memory");
    __builtin_amdgcn_sched_barrier(0);
    __builtin_amdgcn_s_barrier();
    __builtin_amdgcn_sched_barrier(0);
}

__global__ __launch_bounds__(1024, 1) void is_fused_kernel(
    const float* __restrict__ x,      // (L, C, HW)
    const float* __restrict__ mlp_w,  // (1, C)
    const float* __restrict__ mlp_b,  // (1,)
    float* __restrict__ out)          // (L, C, HW)
{
    __shared__ float w_sh[C_SZ];
    __shared__ float part[16][16][8][5];  // [wave][ni16][val k][n-comp], pad 4->5
    __shared__ float m_sh[64];

    const int tid  = threadIdx.x;
    const int wv   = tid >> 6;          // 0..15
    const int lane = tid & 63;
    const int ci4  = lane >> 4;         // 0..3  (channel slice within wave)
    const int ni16 = lane & 15;         // 0..15 (n-position, 4 floats each)

    if (tid < C_SZ) w_sh[tid] = mlp_w[tid];
    sync_lds_only();

    const int cb = 16 * wv + ci4;       // + 4*j
    const float bias = mlp_b[0];
    float wcs[4];
    #pragma unroll
    for (int j = 0; j < 4; ++j) wcs[j] = w_sh[cb + 4 * j];

    #pragma unroll 1
    for (int t = 0; t < 2; ++t) {
        const int n0 = (blockIdx.x * 2 + t) * 64 + ni16 * 4;
        const float* bp = x   + cb * HW_SZ + n0;
        float*       op = out + cb * HW_SZ + n0;

        // ---- phase 1: load everything (20 independent float4 loads) ----
        vfloat4 v[5][4];
        #pragma unroll
        for (int l = 0; l < 5; ++l)
            #pragma unroll
            for (int j = 0; j < 4; ++j)
                v[l][j] = *(const vfloat4*)(bp + l * CHW + j * 4 * HW_SZ);

        // ---- phase 2: per-thread partial dots (4 channels, 4 n each) ----
        vfloat4 s[4] = {{0,0,0,0},{0,0,0,0},{0,0,0,0},{0,0,0,0}};
        vfloat4 tt4[4] = {{0,0,0,0},{0,0,0,0},{0,0,0,0},{0,0,0,0}};
        #pragma unroll
        for (int j = 0; j < 4; ++j) {
            #pragma unroll
            for (int k = 0; k < 4; ++k) {
                s[k]   += v[0][j] * v[k + 1][j];
                tt4[k] += wcs[j]  * v[k + 1][j];
            }
        }

        // ---- ego store early (maskless) — drains under the reduce ----
        #pragma unroll
        for (int j = 0; j < 4; ++j)
            __builtin_nontemporal_store(v[0][j], (vfloat4*)(op + j * 4 * HW_SZ));

        // ---- phase 3: butterfly reduce over ci4 (lane xor 16, 32) ----
        #pragma unroll
        for (int m = 16; m <= 32; m <<= 1) {
            #pragma unroll
            for (int k = 0; k < 4; ++k) {
                #pragma unroll
                for (int c = 0; c < 4; ++c) {
                    s[k][c]   += __shfl_xor(s[k][c], m, 64);
                    tt4[k][c] += __shfl_xor(tt4[k][c], m, 64);
                }
            }
        }
        if (ci4 == 0) {
            #pragma unroll
            for (int k = 0; k < 4; ++k)
                #pragma unroll
                for (int c = 0; c < 4; ++c) {
                    part[wv][ni16][k][c]     = s[k][c];
                    part[wv][ni16][k + 4][c] = tt4[k][c];
                }
        }
        sync_lds_only();

        // ---- phase 4: cross-wave reduce + softmax + gate (64 thr, 1/n) ----
        if (tid < 64) {
            const int g = tid >> 2, cc = tid & 3;
            float ss[4] = {0, 0, 0, 0}, tz[4] = {0, 0, 0, 0};
            #pragma unroll
            for (int w8 = 0; w8 < 16; ++w8) {
                #pragma unroll
                for (int k = 0; k < 4; ++k) {
                    ss[k] += part[w8][g][k][cc];
                    tz[k] += part[w8][g][k + 4][cc];
                }
            }
            const float scale = 0.0625f;   // 1/sqrt(256)
            #pragma unroll
            for (int k = 0; k < 4; ++k) ss[k] *= scale;

            const float smax = fmaxf(fmaxf(ss[0], ss[1]), fmaxf(ss[2], ss[3]));
            const float p0 = expf(ss[0] - smax);
            const float p1 = expf(ss[1] - smax);
            const float p2 = expf(ss[2] - smax);
            const float p3 = expf(ss[3] - smax);
            const float z  = (p0 * tz[0] + p1 * tz[1] + p2 * tz[2] + p3 * tz[3])
                             / ((p0 + p1) + (p2 + p3)) + bias;
            // sigmoid(relu(z)) > 0.5  <=>  z > 0  (exact)
            m_sh[tid] = (z > 0.f) ? 1.f : 0.f;
        }
        sync_lds_only();

        // ---- phase 5: scale + store (16 float4 NT stores, atom-complete),
        //      left in the vmem queue to drain under the next tile's loads --
        const int nl = ni16 * 4;
        vfloat4 m4;
        m4.x = m_sh[nl];     m4.y = m_sh[nl + 1];
        m4.z = m_sh[nl + 2]; m4.w = m_sh[nl + 3];

        #pragma unroll
        for (int l = 1; l < 5; ++l)
            #pragma unroll
            for (int j = 0; j < 4; ++j)
                __builtin_nontemporal_store(v[l][j] * m4,
                                            (vfloat4*)(op + l * CHW + j * 4 * HW_SZ));

        // one more LDS-only barrier so next tile's m_sh/part writes can't
        // race this tile's m_sh reads (readers' lgkmcnt drained here)
        sync_lds_only();
    }
}

extern "C" void kernel_launch(void* const* d_in, const int* in_sizes, int n_in,
                              void* d_out, int out_size, void* d_ws, size_t ws_size,
                              hipStream_t stream) {
    const float* x = (const float*)d_in[0];   // node_feature (5,256,128,256)
    const float* w = (const float*)d_in[1];   // mlp_w (1,256)
    const float* b = (const float*)d_in[2];   // mlp_b (1,)
    float* out = (float*)d_out;

    hipLaunchKernelGGL(is_fused_kernel, dim3(HW_SZ / 128), dim3(1024), 0, stream,
                       x, w, b, out);
}

// Round 5
// 65.514 us; speedup vs baseline: 1.1740x; 1.1740x over previous
//
#include <hip/hip_runtime.h>
#include <math.h>

#define HW_SZ 32768
#define C_SZ  256
#define L_SZ  5
#define CHW   (C_SZ * HW_SZ)     // 8,388,608 elements (int-safe)

typedef float vfloat4 __attribute__((ext_vector_type(4)));

// ---------------------------------------------------------------------------
// R5 = R3 (best, 65.4 us) + vmcnt-paced nt stores. R3 counters showed every
// excess write byte is paired with an excess fetch byte (RMW fill reads):
//   v0: W+44/F 61+44 | R3: W+33/F 66+33 | R4: W+60/F 63+60 | R1: W+0, paced
// R1 (stores interposed 1-per-load) is the only variant with clean 168 MB
// writes -> amplification is caused by the 16 KB/wave store BURST
// overflowing controller write-combining buffers (premature partial-granule
// drain -> RMW). Fix: cap outstanding stores per wave with s_waitcnt
// vmcnt(2) after each 4-store plane group. Everything else identical to R3:
// 1024 thr / 16 waves / 64-n tile / atom-complete 256-B segments / grid 512.
// ---------------------------------------------------------------------------
__global__ __launch_bounds__(1024, 1) void is_fused_kernel(
    const float* __restrict__ x,      // (L, C, HW)
    const float* __restrict__ mlp_w,  // (1, C)
    const float* __restrict__ mlp_b,  // (1,)
    float* __restrict__ out)          // (L, C, HW)
{
    __shared__ float w_sh[C_SZ];
    __shared__ float part[16][16][8][5];  // [wave][ni16][val k][n-comp], pad 4->5
    __shared__ float m_sh[64];

    const int tid  = threadIdx.x;
    const int wv   = tid >> 6;          // 0..15
    const int lane = tid & 63;
    const int ci4  = lane >> 4;         // 0..3  (channel slice within wave)
    const int ni16 = lane & 15;         // 0..15 (n-position, 4 floats each)
    const int n0   = blockIdx.x * 64 + ni16 * 4;

    if (tid < C_SZ) w_sh[tid] = mlp_w[tid];
    __syncthreads();

    const int cb = 16 * wv + ci4;       // + 4*j
    const float* bp = x   + cb * HW_SZ + n0;
    float*       op = out + cb * HW_SZ + n0;

    // ---- phase 1: load everything (20 independent float4 loads) ----
    vfloat4 v[5][4];
    #pragma unroll
    for (int l = 0; l < 5; ++l)
        #pragma unroll
        for (int j = 0; j < 4; ++j)
            v[l][j] = *(const vfloat4*)(bp + l * CHW + j * 4 * HW_SZ);

    // ---- phase 2: per-thread partial dots (4 channels, 4 n each) ----
    vfloat4 s[4] = {{0,0,0,0},{0,0,0,0},{0,0,0,0},{0,0,0,0}};
    vfloat4 t[4] = {{0,0,0,0},{0,0,0,0},{0,0,0,0},{0,0,0,0}};
    #pragma unroll
    for (int j = 0; j < 4; ++j) {
        const float wc = w_sh[cb + 4 * j];
        #pragma unroll
        for (int k = 0; k < 4; ++k) {
            s[k] += v[0][j] * v[k + 1][j];
            t[k] += wc      * v[k + 1][j];
        }
    }

    // ---- ego store early (maskless) — drains under the reduce phase ----
    #pragma unroll
    for (int j = 0; j < 4; ++j)
        __builtin_nontemporal_store(v[0][j], (vfloat4*)(op + j * 4 * HW_SZ));

    // ---- phase 3: butterfly reduce over ci4 (lane xor 16, 32) ----
    #pragma unroll
    for (int m = 16; m <= 32; m <<= 1) {
        #pragma unroll
        for (int k = 0; k < 4; ++k) {
            #pragma unroll
            for (int c = 0; c < 4; ++c) {
                s[k][c] += __shfl_xor(s[k][c], m, 64);
                t[k][c] += __shfl_xor(t[k][c], m, 64);
            }
        }
    }
    if (ci4 == 0) {
        #pragma unroll
        for (int k = 0; k < 4; ++k)
            #pragma unroll
            for (int c = 0; c < 4; ++c) {
                part[wv][ni16][k][c]     = s[k][c];
                part[wv][ni16][k + 4][c] = t[k][c];
            }
    }
    __syncthreads();

    // ---- phase 4: cross-wave reduce + softmax + gate (64 threads, 1/n) ----
    if (tid < 64) {
        const int g = tid >> 2, cc = tid & 3;
        float ss[4] = {0, 0, 0, 0}, tt[4] = {0, 0, 0, 0};
        #pragma unroll
        for (int w8 = 0; w8 < 16; ++w8) {
            #pragma unroll
            for (int k = 0; k < 4; ++k) {
                ss[k] += part[w8][g][k][cc];
                tt[k] += part[w8][g][k + 4][cc];
            }
        }
        const float scale = 0.0625f;   // 1/sqrt(256)
        #pragma unroll
        for (int k = 0; k < 4; ++k) ss[k] *= scale;

        const float smax = fmaxf(fmaxf(ss[0], ss[1]), fmaxf(ss[2], ss[3]));
        const float p0 = expf(ss[0] - smax);
        const float p1 = expf(ss[1] - smax);
        const float p2 = expf(ss[2] - smax);
        const float p3 = expf(ss[3] - smax);
        const float z  = (p0 * tt[0] + p1 * tt[1] + p2 * tt[2] + p3 * tt[3])
                         / ((p0 + p1) + (p2 + p3)) + mlp_b[0];
        // sigmoid(relu(z)) > 0.5  <=>  z > 0  (exact)
        m_sh[tid] = (z > 0.f) ? 1.f : 0.f;
    }
    __syncthreads();

    // ---- phase 5: scale + PACED nt stores (cap ~2-6 outstanding/wave) ----
    const int nl = ni16 * 4;
    vfloat4 m4;
    m4.x = m_sh[nl];     m4.y = m_sh[nl + 1];
    m4.z = m_sh[nl + 2]; m4.w = m_sh[nl + 3];

    #pragma unroll
    for (int l = 1; l < 5; ++l) {
        #pragma unroll
        for (int j = 0; j < 4; ++j)
            __builtin_nontemporal_store(v[l][j] * m4,
                                        (vfloat4*)(op + l * CHW + j * 4 * HW_SZ));
        // pace the burst: wait until <=2 vmem ops outstanding before the
        // next plane group (all loads long since consumed -> counts stores).
        // No wait after the last group: endpgm overlaps drain w/ next block.
        if (l < 4)
            asm volatile("s_waitcnt vmcnt(2)" ::: "memory");
    }
}

extern "C" void kernel_launch(void* const* d_in, const int* in_sizes, int n_in,
                              void* d_out, int out_size, void* d_ws, size_t ws_size,
                              hipStream_t stream) {
    const float* x = (const float*)d_in[0];   // node_feature (5,256,128,256)
    const float* w = (const float*)d_in[1];   // mlp_w (1,256)
    const float* b = (const float*)d_in[2];   // mlp_b (1,)
    float* out = (float*)d_out;

    hipLaunchKernelGGL(is_fused_kernel, dim3(HW_SZ / 64), dim3(1024), 0, stream,
                       x, w, b, out);
}

// Round 7
// 64.570 us; speedup vs baseline: 1.1912x; 1.0146x over previous
//
#include <hip/hip_runtime.h>
#include <math.h>

#define HW_SZ 32768
#define C_SZ  256
#define L_SZ  5
#define CHW   (C_SZ * HW_SZ)     // 8,388,608 elements (int-safe)

typedef float vfloat4 __attribute__((ext_vector_type(4)));

// ---------------------------------------------------------------------------
// R7 = R3 (best, 65.4 us) + chunked XCD blockIdx swizzle.
// Default dispatch round-robins blocks across the 8 XCDs, so adjacent-n
// blocks (whose 256-B store chunks are halves/neighbors of the same >=512-B
// HBM granule, and whose x-reads share DRAM rows) live in DIFFERENT XCD L2s
// -> no TCC merge window -> partial-granule RMW at the controller. This is
// the candidate source of the irreducible write excess (+33 MB) and its
// paired fill reads, which survived atom-complete instructions (R3), pacing
// (R5), and every structural variant at a pinned ~4.7 TB/s.
// Swizzle: swz = (bid%8)*64 + bid/8  (bijective, 512 blocks % 8 == 0).
// Blocks landing on XCD r now own one contiguous 4096-n span: per (l,c) row
// each XCD handles a contiguous 16 KB segment via ~co-resident blocks ->
// store merge + HBM row locality for reads and writes.
// Everything else byte-identical to R3: 1024 thr / 16 waves / 64-n tile /
// atom-complete 256-B nt stores / early ego store.
// ---------------------------------------------------------------------------
__global__ __launch_bounds__(1024, 1) void is_fused_kernel(
    const float* __restrict__ x,      // (L, C, HW)
    const float* __restrict__ mlp_w,  // (1, C)
    const float* __restrict__ mlp_b,  // (1,)
    float* __restrict__ out)          // (L, C, HW)
{
    __shared__ float w_sh[C_SZ];
    __shared__ float part[16][16][8][5];  // [wave][ni16][val k][n-comp], pad 4->5
    __shared__ float m_sh[64];

    const int tid  = threadIdx.x;
    const int wv   = tid >> 6;          // 0..15
    const int lane = tid & 63;
    const int ci4  = lane >> 4;         // 0..3  (channel slice within wave)
    const int ni16 = lane & 15;         // 0..15 (n-position, 4 floats each)

    // chunked XCD swizzle: dispatch round-robin (xcd = bid%8) -> contiguous
    // n-chunk per XCD. 512 blocks, q = 64 per XCD; bijective since 512%8==0.
    const int swz = (blockIdx.x & 7) * (int)(gridDim.x >> 3) + (blockIdx.x >> 3);
    const int n0  = swz * 64 + ni16 * 4;

    if (tid < C_SZ) w_sh[tid] = mlp_w[tid];
    __syncthreads();

    const int cb = 16 * wv + ci4;       // + 4*j
    const float* bp = x   + cb * HW_SZ + n0;
    float*       op = out + cb * HW_SZ + n0;

    // ---- phase 1: load everything (20 independent float4 loads) ----
    vfloat4 v[5][4];
    #pragma unroll
    for (int l = 0; l < 5; ++l)
        #pragma unroll
        for (int j = 0; j < 4; ++j)
            v[l][j] = *(const vfloat4*)(bp + l * CHW + j * 4 * HW_SZ);

    // ---- phase 2: per-thread partial dots (4 channels, 4 n each) ----
    vfloat4 s[4] = {{0,0,0,0},{0,0,0,0},{0,0,0,0},{0,0,0,0}};
    vfloat4 t[4] = {{0,0,0,0},{0,0,0,0},{0,0,0,0},{0,0,0,0}};
    #pragma unroll
    for (int j = 0; j < 4; ++j) {
        const float wc = w_sh[cb + 4 * j];
        #pragma unroll
        for (int k = 0; k < 4; ++k) {
            s[k] += v[0][j] * v[k + 1][j];
            t[k] += wc      * v[k + 1][j];
        }
    }

    // ---- ego store early (maskless) — drains under the reduce phase ----
    #pragma unroll
    for (int j = 0; j < 4; ++j)
        __builtin_nontemporal_store(v[0][j], (vfloat4*)(op + j * 4 * HW_SZ));

    // ---- phase 3: butterfly reduce over ci4 (lane xor 16, 32) ----
    #pragma unroll
    for (int m = 16; m <= 32; m <<= 1) {
        #pragma unroll
        for (int k = 0; k < 4; ++k) {
            #pragma unroll
            for (int c = 0; c < 4; ++c) {
                s[k][c] += __shfl_xor(s[k][c], m, 64);
                t[k][c] += __shfl_xor(t[k][c], m, 64);
            }
        }
    }
    if (ci4 == 0) {
        #pragma unroll
        for (int k = 0; k < 4; ++k)
            #pragma unroll
            for (int c = 0; c < 4; ++c) {
                part[wv][ni16][k][c]     = s[k][c];
                part[wv][ni16][k + 4][c] = t[k][c];
            }
    }
    __syncthreads();

    // ---- phase 4: cross-wave reduce + softmax + gate (64 threads, 1/n) ----
    if (tid < 64) {
        const int g = tid >> 2, cc = tid & 3;
        float ss[4] = {0, 0, 0, 0}, tt[4] = {0, 0, 0, 0};
        #pragma unroll
        for (int w8 = 0; w8 < 16; ++w8) {
            #pragma unroll
            for (int k = 0; k < 4; ++k) {
                ss[k] += part[w8][g][k][cc];
                tt[k] += part[w8][g][k + 4][cc];
            }
        }
        const float scale = 0.0625f;   // 1/sqrt(256)
        #pragma unroll
        for (int k = 0; k < 4; ++k) ss[k] *= scale;

        const float smax = fmaxf(fmaxf(ss[0], ss[1]), fmaxf(ss[2], ss[3]));
        const float p0 = expf(ss[0] - smax);
        const float p1 = expf(ss[1] - smax);
        const float p2 = expf(ss[2] - smax);
        const float p3 = expf(ss[3] - smax);
        const float z  = (p0 * tt[0] + p1 * tt[1] + p2 * tt[2] + p3 * tt[3])
                         / ((p0 + p1) + (p2 + p3)) + mlp_b[0];
        // sigmoid(relu(z)) > 0.5  <=>  z > 0  (exact)
        m_sh[tid] = (z > 0.f) ? 1.f : 0.f;
    }
    __syncthreads();

    // ---- phase 5: scale + store (16 float4 NT stores, atom-complete) ----
    const int nl = ni16 * 4;
    vfloat4 m4;
    m4.x = m_sh[nl];     m4.y = m_sh[nl + 1];
    m4.z = m_sh[nl + 2]; m4.w = m_sh[nl + 3];

    #pragma unroll
    for (int l = 1; l < 5; ++l)
        #pragma unroll
        for (int j = 0; j < 4; ++j)
            __builtin_nontemporal_store(v[l][j] * m4,
                                        (vfloat4*)(op + l * CHW + j * 4 * HW_SZ));
}

extern "C" void kernel_launch(void* const* d_in, const int* in_sizes, int n_in,
                              void* d_out, int out_size, void* d_ws, size_t ws_size,
                              hipStream_t stream) {
    const float* x = (const float*)d_in[0];   // node_feature (5,256,128,256)
    const float* w = (const float*)d_in[1];   // mlp_w (1,256)
    const float* b = (const float*)d_in[2];   // mlp_b (1,)
    float* out = (float*)d_out;

    hipLaunchKernelGGL(is_fused_kernel, dim3(HW_SZ / 64), dim3(1024), 0, stream,
                       x, w, b, out);
}